// Round 10
// baseline (670.501 us; speedup 1.0000x reference)
//
#include <hip/hip_runtime.h>

// GAT 3-layer forward on MI355X — round 10.
// vs round 9 (best, 653.7us): PairNorm mean-subtract folded into the next GEMM as a
// rank-1 correction (cmw[col] = colmean @ W_ext; (v-m)@W = v@W - cmw) -> sub_k and the
// hbf array are gone; GEMM-0 consumes fp32 x directly (cast kernel gone); residual
// halves stored f16 (halves res traffic); fill_pack x3 merged into one launch.
// aggregate4 left untouched: R6/R9 showed it is gather-fabric-bound (~84us at 260MB
// FETCH = 1.27x the 8-XCD compulsory floor), insensitive to VALU cuts.

typedef __attribute__((ext_vector_type(8))) short s8v;
typedef __attribute__((ext_vector_type(4))) float f4v;
typedef __attribute__((ext_vector_type(2))) _Float16 h2;
typedef __attribute__((ext_vector_type(4))) _Float16 h4;

__device__ __forceinline__ unsigned short f2bf(float f) {
  unsigned int x = __float_as_uint(f);
  x += 0x7fffu + ((x >> 16) & 1u);          // RTNE
  return (unsigned short)(x >> 16);
}
__device__ __forceinline__ float bf2f(unsigned short u) {
  return __uint_as_float(((unsigned int)u) << 16);
}
__device__ __forceinline__ unsigned short f2h(float f) {
  _Float16 h = (_Float16)f;
  return __builtin_bit_cast(unsigned short, h);
}
__device__ __forceinline__ float lrelu(float x) { return fmaxf(x, 0.2f * x); }
__device__ __forceinline__ float elu1(float x) { return x > 0.f ? x : expm1f(x); }

// ---------------- CSR build (padded to multiples of 16 per node) ----------------
__global__ __launch_bounds__(256) void hist_k(const int* __restrict__ dst, int* __restrict__ counts, int E) {
  int t = blockIdx.x * 256 + threadIdx.x;
  if (t < E) atomicAdd(&counts[dst[t]], 1);
}

__global__ __launch_bounds__(256) void scan1(const int* __restrict__ counts, int* __restrict__ rsp,
                                             int* __restrict__ bsum, int Nn) {
  __shared__ int s[256];
  int t = threadIdx.x;
  int base = blockIdx.x * 1024 + t * 4;
  int v0 = (base + 0 < Nn) ? ((counts[base + 0] + 15) & ~15) : 0;
  int v1 = (base + 1 < Nn) ? ((counts[base + 1] + 15) & ~15) : 0;
  int v2 = (base + 2 < Nn) ? ((counts[base + 2] + 15) & ~15) : 0;
  int v3 = (base + 3 < Nn) ? ((counts[base + 3] + 15) & ~15) : 0;
  s[t] = v0 + v1 + v2 + v3;
  __syncthreads();
  for (int off = 1; off < 256; off <<= 1) {
    int xv = (t >= off) ? s[t - off] : 0;
    __syncthreads();
    s[t] += xv;
    __syncthreads();
  }
  int excl = t ? s[t - 1] : 0;
  if (t == 255) bsum[blockIdx.x] = s[255];
  if (base + 0 < Nn) { rsp[base + 0] = excl; excl += v0; }
  if (base + 1 < Nn) { rsp[base + 1] = excl; excl += v1; }
  if (base + 2 < Nn) { rsp[base + 2] = excl; excl += v2; }
  if (base + 3 < Nn) { rsp[base + 3] = excl; }
}

__global__ __launch_bounds__(128) void scan2(int* __restrict__ bsum, int nb) {
  __shared__ int s[128];
  int t = threadIdx.x;
  s[t] = (t < nb) ? bsum[t] : 0;
  __syncthreads();
  for (int off = 1; off < 128; off <<= 1) {
    int xv = (t >= off) ? s[t - off] : 0;
    __syncthreads();
    s[t] += xv;
    __syncthreads();
  }
  if (t < nb) bsum[t] = t ? s[t - 1] : 0;
}

__global__ __launch_bounds__(256) void scan3(int* __restrict__ rsp, const int* __restrict__ bsum,
                                             int* __restrict__ cursor, int Nn) {
  int t = blockIdx.x * 256 + threadIdx.x;
  if (t < Nn) {
    int v = rsp[t] + bsum[t >> 10];
    rsp[t] = v;
    cursor[t] = v;
  }
}

// XCD-affine scatter: bucket p = blockIdx&7 -> each csr region owned by one XCD L2.
__global__ __launch_bounds__(256) void pscatter_k(const int* __restrict__ src, const int* __restrict__ dst,
                                                  int* __restrict__ cursor, int* __restrict__ csr_src,
                                                  int E, int shift) {
  int p = blockIdx.x & 7;
  int pb = blockIdx.x >> 3;
  int stride = (gridDim.x >> 3) * 256;
  for (int e = pb * 256 + threadIdx.x; e < E; e += stride) {
    int d = dst[e];
    if ((d >> shift) == p) {
      int pos = atomicAdd(&cursor[d], 1);
      csr_src[pos] = src[e];
    }
  }
}

// ---------------- fused weight pack (all 3 layers, one launch) ----------------
__device__ __forceinline__ void pack_one(const float* W, const float* al, const float* ar,
                                         const float* resW, unsigned short* out,
                                         int K, int M, int BF, int H, int RES0, int t) {
  int c = t / K, k = t - c * K;
  float v = 0.f;
  if (c < BF) {
    v = W[k * BF + c];
  } else if (c < BF + H) {
    int h = c - BF;
    float s = 0.f;
    for (int d = 0; d < 32; d++) s += W[k * BF + h * 32 + d] * al[h * 32 + d];
    v = s;
  } else if (c < BF + 2 * H) {
    int h = c - BF - H;
    float s = 0.f;
    for (int d = 0; d < 32; d++) s += W[k * BF + h * 32 + d] * ar[h * 32 + d];
    v = s;
  } else if (c >= RES0) {
    v = resW[k * (M - RES0) + (c - RES0)];
  }
  unsigned short hi = f2bf(v);
  out[c * K + k] = hi;
  out[M * K + c * K + k] = f2bf(v - bf2f(hi));
}

__global__ __launch_bounds__(256) void fill_all(const float* __restrict__ W0, const float* __restrict__ al0,
                                                const float* __restrict__ ar0,
                                                const float* __restrict__ W1, const float* __restrict__ al1,
                                                const float* __restrict__ ar1, const float* __restrict__ resW1,
                                                const float* __restrict__ W2, const float* __restrict__ al2,
                                                const float* __restrict__ ar2, const float* __restrict__ resW2,
                                                unsigned short* __restrict__ w0t, unsigned short* __restrict__ w1t,
                                                unsigned short* __restrict__ w2t) {
  const int n0 = 144 * 64, n1 = 272 * 128, n2 = 80 * 128;
  int t = blockIdx.x * 256 + threadIdx.x;
  if (t < n0) {
    pack_one(W0, al0, ar0, nullptr, w0t, 64, 144, 128, 4, 144, t);
  } else if (t < n0 + n1) {
    pack_one(W1, al1, ar1, resW1, w1t, 128, 272, 128, 4, 144, t - n0);
  } else if (t < n0 + n1 + n2) {
    pack_one(W2, al2, ar2, resW2, w2t, 128, 80, 32, 1, 48, t - n0 - n1);
  }
}

// ---------------- cmw[col] = invN * colsum @ (W_hi + W_lo)  (rank-1 PairNorm fold) ----------------
__global__ __launch_bounds__(256) void cmw_k(const float* __restrict__ colsum,
                                             const unsigned short* __restrict__ wt,
                                             float* __restrict__ cmw, int K, int M, float invN) {
  int c = blockIdx.x * 256 + threadIdx.x;
  if (c >= M) return;
  float s = 0.f;
  for (int k = 0; k < K; k++)
    s += colsum[k] * (bf2f(wt[c * K + k]) + bf2f(wt[(size_t)M * K + c * K + k]));
  cmw[c] = s * invN;
}

// ---------------- GEMM: A[N,K] @ Bt[M,K](bf16 hi+lo); epilogue: -cmw, route cols ----------------
// AF32: A is fp32 (layer 0 reads x directly, converts to bf16 frags in-register).
// CMW:  subtract cmw[col] (PairNorm colmean fold) before routing.
template <int K, int M, int R, int BF, int H, int RES0, bool AF32, bool CMW>
__global__ __launch_bounds__(256) void gemm_bf16(const void* __restrict__ Av,
                                                 const unsigned short* __restrict__ Bt,
                                                 const float* __restrict__ cmw,
                                                 unsigned short* __restrict__ feath,
                                                 float* __restrict__ el, float* __restrict__ er,
                                                 unsigned short* __restrict__ resh, int nRowTiles) {
  int wv = (int)((blockIdx.x * blockDim.x + threadIdx.x) >> 6);
  int tile0 = wv * R;
  if (tile0 >= nRowTiles) return;
  int lane = threadIdx.x & 63;
  int r = lane & 15, q = lane >> 4;
  s8v afrag[R][K / 32];
#pragma unroll
  for (int rr = 0; rr < R; rr++) {
    if constexpr (AF32) {
      const float* arow = (const float*)Av + (size_t)((tile0 + rr) * 16 + r) * K + q * 8;
#pragma unroll
      for (int kk = 0; kk < K / 32; kk++) {
        s8v v;
#pragma unroll
        for (int j = 0; j < 8; j++) v[j] = (short)f2bf(arow[kk * 32 + j]);
        afrag[rr][kk] = v;
      }
    } else {
      const unsigned short* arow = (const unsigned short*)Av + (size_t)((tile0 + rr) * 16 + r) * K + q * 8;
#pragma unroll
      for (int kk = 0; kk < K / 32; kk++) afrag[rr][kk] = *(const s8v*)(arow + kk * 32);
    }
  }
#pragma unroll
  for (int ct = 0; ct < M / 16; ct++) {
    const unsigned short* brow = Bt + (size_t)(ct * 16 + r) * K + q * 8;
    s8v bhi[K / 32], blo[K / 32];
#pragma unroll
    for (int kk = 0; kk < K / 32; kk++) {
      bhi[kk] = *(const s8v*)(brow + kk * 32);
      blo[kk] = *(const s8v*)(brow + (size_t)M * K + kk * 32);
    }
    int col = ct * 16 + r;
    float cmwv = 0.f;
    if constexpr (CMW) cmwv = cmw[col];
#pragma unroll
    for (int rr = 0; rr < R; rr++) {
      f4v acc = {0.f, 0.f, 0.f, 0.f};
#pragma unroll
      for (int kk = 0; kk < K / 32; kk++) {
        acc = __builtin_amdgcn_mfma_f32_16x16x32_bf16(afrag[rr][kk], bhi[kk], acc, 0, 0, 0);
        acc = __builtin_amdgcn_mfma_f32_16x16x32_bf16(afrag[rr][kk], blo[kk], acc, 0, 0, 0);
      }
      int row0 = (tile0 + rr) * 16 + q * 4;
#pragma unroll
      for (int i = 0; i < 4; i++) {
        float v = acc[i] - cmwv;
        size_t row = (size_t)(row0 + i);
        if (col < BF) {
          feath[row * BF + col] = f2h(v);
        } else if (col < BF + H) {
          el[row * H + (col - BF)] = v;
        } else if (col < BF + 2 * H) {
          er[row * H + (col - BF - H)] = v;
        } else if (RES0 < M && col >= RES0) {
          resh[row * (M - RES0) + (col - RES0)] = f2h(v);
        }
      }
    }
  }
}

// ---------------- fused single-pass aggregation H=4 (R9 structure, f16 res) ----------------
template <int MODE>
__global__ __launch_bounds__(256) void aggregate4(const unsigned short* __restrict__ feath,
                                                  const float* __restrict__ el4,
                                                  const float* __restrict__ er4,
                                                  const int* __restrict__ csr_src,
                                                  const int* __restrict__ rsp,
                                                  const int* __restrict__ counts,
                                                  const unsigned short* __restrict__ resh,
                                                  unsigned short* __restrict__ vbf,
                                                  float* __restrict__ rnrm, int Nn) {
  int n = (int)((blockIdx.x * blockDim.x + threadIdx.x) >> 6);
  if (n >= Nn) return;
  int lane = threadIdx.x & 63;
  int start = __builtin_amdgcn_readfirstlane(rsp[n]);
  int deg = __builtin_amdgcn_readfirstlane(counts[n]);
  int chunks = (deg + 15) >> 4;
  int slot = lane >> 2, h = lane & 3;
  float ern = er4[(size_t)n * 4 + h];
  int hl = lane >> 4;                        // head of lane's dims (dims 2l..2l+1)
  unsigned dby = (unsigned)lane << 2;        // byte offset into 256B f16 row
  float a0 = 0.f, a1 = 0.f, dsum = 0.f;
  for (int c = 0; c < chunks; c++) {
    const int* csp = csr_src + start + (c << 4);
    // phase A: one (edge,head) per lane
    int sA = csp[slot];
    float exv = 0.f;
    if (((c << 4) + slot) < deg) {
      float e = el4[(size_t)sA * 4 + h] + ern;
      exv = __expf(fmaxf(e, 0.2f * e));
    }
    dsum += exv;
    // phase B: batch all 16 csr reads first (independent loads in flight)
    int sj[16];
#pragma unroll
    for (int j = 0; j < 16; j++) sj[j] = csp[j];
#pragma unroll
    for (int j = 0; j < 16; j++) {
      float aw = __shfl(exv, (j << 2) | hl);
      h2 fv = *(const h2*)((const char*)feath + (((unsigned)sj[j] << 8) + dby));
      a0 = fmaf((float)fv[0], aw, a0);
      a1 = fmaf((float)fv[1], aw, a1);
    }
  }
  // per-head denominator totals: after butterfly, lane l holds head (l&3) total
#pragma unroll
  for (int off = 4; off < 64; off <<= 1) dsum += __shfl_xor(dsum, off);
  float inv = dsum > 0.f ? 1.f / dsum : 0.f;
  float invh = __shfl(inv, hl);
  float v0, v1;
  if (MODE == 1) {
    h2 rr = *(const h2*)(resh + (size_t)n * 128 + lane * 2);
    v0 = elu1(elu1(a0 * invh + (float)rr[0]));
    v1 = elu1(elu1(a1 * invh + (float)rr[1]));
  } else {
    v0 = elu1(a0 * invh);
    v1 = elu1(a1 * invh);
  }
  float ss = v0 * v0 + v1 * v1;
#pragma unroll
  for (int off = 1; off < 64; off <<= 1) ss += __shfl_xor(ss, off);
  float rn = sqrtf(1e-6f + ss);
  float ri = 1.f / rn;
  unsigned int pk = (unsigned int)f2bf(v0 * ri) | ((unsigned int)f2bf(v1 * ri) << 16);
  *(unsigned int*)((char*)vbf + ((size_t)n << 8) + (lane << 2)) = pk;
  if (lane == 0) rnrm[n] = rn;
}

// ---------------- fused single-pass aggregation H=1 (layer 2, f16 feat + f16 res) ----------------
__global__ __launch_bounds__(256) void aggregate1(const unsigned short* __restrict__ feath,
                                                  const float* __restrict__ el1,
                                                  const float* __restrict__ er1,
                                                  const int* __restrict__ csr_src,
                                                  const int* __restrict__ rsp,
                                                  const int* __restrict__ counts,
                                                  const unsigned short* __restrict__ res2h,
                                                  float* __restrict__ out2, int Nn) {
  int n = (int)((blockIdx.x * blockDim.x + threadIdx.x) >> 6);
  if (n >= Nn) return;
  int lane = threadIdx.x & 63;
  int start = __builtin_amdgcn_readfirstlane(rsp[n]);
  int deg = __builtin_amdgcn_readfirstlane(counts[n]);
  int chunks = (deg + 15) >> 4;
  int l16 = lane & 15;
  float ern = er1[n];
  int g = lane >> 3;                          // 8 edge groups (2 edges each per chunk)
  unsigned dofs8 = (unsigned)(lane & 7) << 3; // byte offset into 64B f16 row
  f4v acc = {0.f, 0.f, 0.f, 0.f};
  float dsum = 0.f;
  for (int c = 0; c < chunks; c++) {
    const int* csp = csr_src + start + (c << 4);
    int sA = csp[l16];
    float exv = 0.f;
    if (((c << 4) + l16) < deg) exv = __expf(lrelu(el1[sA] + ern));
    dsum += exv;
#pragma unroll
    for (int t = 0; t < 2; t++) {
      int j = (t << 3) + g;
      int sj = __shfl(sA, j);
      float aw = __shfl(exv, j);
      h4 fv = *(const h4*)((const char*)feath + (((unsigned)sj << 6) + dofs8));
      acc[0] = fmaf((float)fv[0], aw, acc[0]);
      acc[1] = fmaf((float)fv[1], aw, acc[1]);
      acc[2] = fmaf((float)fv[2], aw, acc[2]);
      acc[3] = fmaf((float)fv[3], aw, acc[3]);
    }
  }
#pragma unroll
  for (int off = 1; off < 16; off <<= 1) dsum += __shfl_xor(dsum, off);
  float inv = dsum > 0.f ? 1.f / dsum : 0.f;
#pragma unroll
  for (int off = 8; off < 64; off <<= 1) {
    acc[0] += __shfl_xor(acc[0], off);
    acc[1] += __shfl_xor(acc[1], off);
    acc[2] += __shfl_xor(acc[2], off);
    acc[3] += __shfl_xor(acc[3], off);
  }
  if (lane < 8) {
    h4 rr = *(const h4*)(res2h + (size_t)n * 32 + (lane << 2));
    float4 o;
    o.x = acc[0] * inv + (float)rr[0];
    o.y = acc[1] * inv + (float)rr[1];
    o.z = acc[2] * inv + (float)rr[2];
    o.w = acc[3] * inv + (float)rr[3];
    *(float4*)(out2 + (size_t)n * 32 + (lane << 2)) = o;
  }
}

// ---------------- colsum of raw v = vbf * rnrm (PairNorm colmean numerator) ----------------
__global__ __launch_bounds__(256) void colsum_k(const unsigned short* __restrict__ vbf,
                                                const float* __restrict__ rnrm,
                                                float* __restrict__ colsum, int Nn) {
  __shared__ float ls[256];
  int tid = threadIdx.x;
  int c = tid & 127, rsub = tid >> 7;
  float cs = 0.f;
  for (int r = blockIdx.x * 2 + rsub; r < Nn; r += gridDim.x * 2)
    cs += bf2f(vbf[(size_t)r * 128 + c]) * rnrm[r];
  ls[tid] = cs;
  __syncthreads();
  if (tid < 128) atomicAdd(&colsum[tid], ls[tid] + ls[tid + 128]);
}

// ---------------- final: mean over nodes of out2 ----------------
__global__ __launch_bounds__(256) void final_reduce(const float* __restrict__ out2,
                                                    float* __restrict__ outsum, int Nn) {
  __shared__ float ls[32];
  if (threadIdx.x < 32) ls[threadIdx.x] = 0.f;
  __syncthreads();
  int d = threadIdx.x & 31, rl = threadIdx.x >> 5;
  float acc = 0.f;
  for (int n = blockIdx.x * 8 + rl; n < Nn; n += gridDim.x * 8)
    acc += out2[(size_t)n * 32 + d];
  atomicAdd(&ls[d], acc);
  __syncthreads();
  if (threadIdx.x < 32) atomicAdd(&outsum[threadIdx.x], ls[threadIdx.x]);
}

__global__ void finalize_k(const float* __restrict__ outsum, float* __restrict__ out, float invN) {
  int t = threadIdx.x;
  if (t < 32) out[t] = outsum[t] * invN;
}

// ---------------- launcher ----------------
extern "C" void kernel_launch(void* const* d_in, const int* in_sizes, int n_in,
                              void* d_out, int out_size, void* d_ws, size_t ws_size,
                              hipStream_t stream) {
  const float* x     = (const float*)d_in[0];
  const int*   src   = (const int*)d_in[1];
  const int*   dst   = (const int*)d_in[2];
  const float* W0    = (const float*)d_in[3];
  const float* al0   = (const float*)d_in[4];
  const float* ar0   = (const float*)d_in[5];
  const float* W1    = (const float*)d_in[6];
  const float* al1   = (const float*)d_in[7];
  const float* ar1   = (const float*)d_in[8];
  const float* resW1 = (const float*)d_in[9];
  const float* W2    = (const float*)d_in[10];
  const float* al2   = (const float*)d_in[11];
  const float* ar2   = (const float*)d_in[12];
  const float* resW2 = (const float*)d_in[13];
  const int N = in_sizes[0] / 64;   // 100000
  const int E = in_sizes[1];        // 1600000
  const float invN = 1.f / (float)N;
  const int Emax = E + 15 * N + 1024;   // upper bound on padded slot count + margin
  int shift = 0;
  while (((unsigned)(N - 1) >> shift) > 7u) shift++;   // 8 dst-range buckets

  char* p = (char*)d_ws;
  auto alloc = [&](size_t bytes) { char* r = p; p += (bytes + 255) & ~(size_t)255; return r; };

  // zero-initialized region
  char* zbase = p;
  int*   counts  = (int*)alloc((size_t)4 * N);
  float* colsumA = (float*)alloc(512);
  float* colsumB = (float*)alloc(512);
  float* outsum  = (float*)alloc(128);
  size_t zbytes = (size_t)(p - zbase);

  int* rsp    = (int*)alloc((size_t)4 * N);     // padded row starts
  int* cursor = (int*)alloc((size_t)4 * N);
  int* bsum   = (int*)alloc(512);
  int* csr_src = (int*)alloc((size_t)4 * Emax);     // memset 0: pads -> node 0, alpha 0
  unsigned short* feath  = (unsigned short*)alloc((size_t)2 * N * 128);
  unsigned short* vbf    = (unsigned short*)alloc((size_t)2 * N * 128);
  unsigned short* resh   = (unsigned short*)alloc((size_t)2 * N * 128);  // f16 residuals
  unsigned short* w0t = (unsigned short*)alloc((size_t)2 * 2 * 144 * 64);
  unsigned short* w1t = (unsigned short*)alloc((size_t)2 * 2 * 272 * 128);
  unsigned short* w2t = (unsigned short*)alloc((size_t)2 * 2 * 80 * 128);
  float* el4  = (float*)alloc((size_t)16 * N);
  float* er4  = (float*)alloc((size_t)16 * N);
  float* rnrm = (float*)alloc((size_t)4 * N);
  float* cmw1 = (float*)alloc(4 * 272);
  float* cmw2 = (float*)alloc(4 * 80);
  float* out2 = (float*)alloc((size_t)4 * N * 32);   // layer-2 output [N][32]

  hipMemsetAsync(zbase, 0, zbytes, stream);
  hipMemsetAsync(csr_src, 0, (size_t)4 * Emax, stream);

  // CSR build (padded)
  int eb = (E + 255) / 256;
  int nb1024 = (N + 1023) / 1024;
  hist_k<<<eb, 256, 0, stream>>>(dst, counts, E);
  scan1<<<nb1024, 256, 0, stream>>>(counts, rsp, bsum, N);
  scan2<<<1, 128, 0, stream>>>(bsum, nb1024);
  scan3<<<(N + 255) / 256, 256, 0, stream>>>(rsp, bsum, cursor, N);
  pscatter_k<<<1024, 256, 0, stream>>>(src, dst, cursor, csr_src, E, shift);

  // weights: [W | W@al | W@ar | pad | resW] transposed, bf16 hi+lo — one launch
  const int packTot = 144 * 64 + 272 * 128 + 80 * 128;
  fill_all<<<(packTot + 255) / 256, 256, 0, stream>>>(W0, al0, ar0, W1, al1, ar1, resW1,
                                                      W2, al2, ar2, resW2, w0t, w1t, w2t);

  const int rowTiles = N / 16;                  // 6250, divisible by R=5
  const int gblocks = (rowTiles / 5 + 3) / 4;   // 1250 waves, 4/block
  const int aggblocks = (N + 3) / 4;            // wave per node

  // Layer 0 (A = x fp32, no colmean fold)
  gemm_bf16<64, 144, 5, 128, 4, 144, true, false><<<gblocks, 256, 0, stream>>>(
      x, w0t, nullptr, feath, el4, er4, nullptr, rowTiles);
  aggregate4<0><<<aggblocks, 256, 0, stream>>>(feath, el4, er4, csr_src, rsp, counts, nullptr, vbf, rnrm, N);
  colsum_k<<<512, 256, 0, stream>>>(vbf, rnrm, colsumA, N);
  cmw_k<<<2, 256, 0, stream>>>(colsumA, w1t, cmw1, 128, 272, invN);

  // Layer 1 (A = vbf, colmean folded via cmw1)
  gemm_bf16<128, 272, 5, 128, 4, 144, false, true><<<gblocks, 256, 0, stream>>>(
      vbf, w1t, cmw1, feath, el4, er4, resh, rowTiles);
  aggregate4<1><<<aggblocks, 256, 0, stream>>>(feath, el4, er4, csr_src, rsp, counts, resh, vbf, rnrm, N);
  colsum_k<<<512, 256, 0, stream>>>(vbf, rnrm, colsumB, N);
  cmw_k<<<1, 256, 0, stream>>>(colsumB, w2t, cmw2, 128, 80, invN);

  // Layer 2 (A = vbf, colmean folded via cmw2)
  gemm_bf16<128, 80, 5, 32, 1, 48, false, true><<<gblocks, 256, 0, stream>>>(
      vbf, w2t, cmw2, feath, el4, er4, resh, rowTiles);
  aggregate1<<<aggblocks, 256, 0, stream>>>(feath, el4, er4, csr_src, rsp, counts, resh, out2, N);
  final_reduce<<<512, 256, 0, stream>>>(out2, outsum, N);
  finalize_k<<<1, 64, 0, stream>>>(outsum, (float*)d_out, invN);
}

// Round 11
// 644.517 us; speedup vs baseline: 1.0403x; 1.0403x over previous
//
#include <hip/hip_runtime.h>

// GAT 3-layer forward on MI355X — round 11.
// vs round 10: gather table stored as fp8-e4m3 (HW cvt_pk_fp8 encode in GEMM epilogue,
// cvt_pk_f32_fp8 decode in aggregation). agg4 is fetch-fabric-bound (R6 vs R9: 12-pt
// VALU cut -> 0 time change; FETCH 245MB = 1.2x the 8-XCD compulsory floor of the f16
// table). fp8 halves the floor; layer-2 table (3.2MB) now fits one XCD L2. R10's
// rank-1 PairNorm fold dropped absmax to 1.5e-5, giving 23x margin to spend on fp8
// message quantization (predicted ~1e-4 vs 3.54e-4 threshold).

typedef __attribute__((ext_vector_type(8))) short s8v;
typedef __attribute__((ext_vector_type(4))) float f4v;
typedef __attribute__((ext_vector_type(2))) float f2v;
typedef __attribute__((ext_vector_type(2))) _Float16 h2;
typedef __attribute__((ext_vector_type(4))) _Float16 h4;

__device__ __forceinline__ unsigned short f2bf(float f) {
  unsigned int x = __float_as_uint(f);
  x += 0x7fffu + ((x >> 16) & 1u);          // RTNE
  return (unsigned short)(x >> 16);
}
__device__ __forceinline__ float bf2f(unsigned short u) {
  return __uint_as_float(((unsigned int)u) << 16);
}
__device__ __forceinline__ unsigned short f2h(float f) {
  _Float16 h = (_Float16)f;
  return __builtin_bit_cast(unsigned short, h);
}
__device__ __forceinline__ unsigned char f2fp8(float v) {
  return (unsigned char)(__builtin_amdgcn_cvt_pk_fp8_f32(v, v, 0, false) & 0xff);
}
__device__ __forceinline__ float lrelu(float x) { return fmaxf(x, 0.2f * x); }
__device__ __forceinline__ float elu1(float x) { return x > 0.f ? x : expm1f(x); }

// ---------------- CSR build (padded to multiples of 16 per node) ----------------
__global__ __launch_bounds__(256) void hist_k(const int* __restrict__ dst, int* __restrict__ counts, int E) {
  int t = blockIdx.x * 256 + threadIdx.x;
  if (t < E) atomicAdd(&counts[dst[t]], 1);
}

__global__ __launch_bounds__(256) void scan1(const int* __restrict__ counts, int* __restrict__ rsp,
                                             int* __restrict__ bsum, int Nn) {
  __shared__ int s[256];
  int t = threadIdx.x;
  int base = blockIdx.x * 1024 + t * 4;
  int v0 = (base + 0 < Nn) ? ((counts[base + 0] + 15) & ~15) : 0;
  int v1 = (base + 1 < Nn) ? ((counts[base + 1] + 15) & ~15) : 0;
  int v2 = (base + 2 < Nn) ? ((counts[base + 2] + 15) & ~15) : 0;
  int v3 = (base + 3 < Nn) ? ((counts[base + 3] + 15) & ~15) : 0;
  s[t] = v0 + v1 + v2 + v3;
  __syncthreads();
  for (int off = 1; off < 256; off <<= 1) {
    int xv = (t >= off) ? s[t - off] : 0;
    __syncthreads();
    s[t] += xv;
    __syncthreads();
  }
  int excl = t ? s[t - 1] : 0;
  if (t == 255) bsum[blockIdx.x] = s[255];
  if (base + 0 < Nn) { rsp[base + 0] = excl; excl += v0; }
  if (base + 1 < Nn) { rsp[base + 1] = excl; excl += v1; }
  if (base + 2 < Nn) { rsp[base + 2] = excl; excl += v2; }
  if (base + 3 < Nn) { rsp[base + 3] = excl; }
}

__global__ __launch_bounds__(128) void scan2(int* __restrict__ bsum, int nb) {
  __shared__ int s[128];
  int t = threadIdx.x;
  s[t] = (t < nb) ? bsum[t] : 0;
  __syncthreads();
  for (int off = 1; off < 128; off <<= 1) {
    int xv = (t >= off) ? s[t - off] : 0;
    __syncthreads();
    s[t] += xv;
    __syncthreads();
  }
  if (t < nb) bsum[t] = t ? s[t - 1] : 0;
}

__global__ __launch_bounds__(256) void scan3(int* __restrict__ rsp, const int* __restrict__ bsum,
                                             int* __restrict__ cursor, int Nn) {
  int t = blockIdx.x * 256 + threadIdx.x;
  if (t < Nn) {
    int v = rsp[t] + bsum[t >> 10];
    rsp[t] = v;
    cursor[t] = v;
  }
}

// XCD-affine scatter: bucket p = blockIdx&7 -> each csr region owned by one XCD L2.
__global__ __launch_bounds__(256) void pscatter_k(const int* __restrict__ src, const int* __restrict__ dst,
                                                  int* __restrict__ cursor, int* __restrict__ csr_src,
                                                  int E, int shift) {
  int p = blockIdx.x & 7;
  int pb = blockIdx.x >> 3;
  int stride = (gridDim.x >> 3) * 256;
  for (int e = pb * 256 + threadIdx.x; e < E; e += stride) {
    int d = dst[e];
    if ((d >> shift) == p) {
      int pos = atomicAdd(&cursor[d], 1);
      csr_src[pos] = src[e];
    }
  }
}

// ---------------- fused weight pack (all 3 layers, one launch) ----------------
__device__ __forceinline__ void pack_one(const float* W, const float* al, const float* ar,
                                         const float* resW, unsigned short* out,
                                         int K, int M, int BF, int H, int RES0, int t) {
  int c = t / K, k = t - c * K;
  float v = 0.f;
  if (c < BF) {
    v = W[k * BF + c];
  } else if (c < BF + H) {
    int h = c - BF;
    float s = 0.f;
    for (int d = 0; d < 32; d++) s += W[k * BF + h * 32 + d] * al[h * 32 + d];
    v = s;
  } else if (c < BF + 2 * H) {
    int h = c - BF - H;
    float s = 0.f;
    for (int d = 0; d < 32; d++) s += W[k * BF + h * 32 + d] * ar[h * 32 + d];
    v = s;
  } else if (c >= RES0) {
    v = resW[k * (M - RES0) + (c - RES0)];
  }
  unsigned short hi = f2bf(v);
  out[c * K + k] = hi;
  out[M * K + c * K + k] = f2bf(v - bf2f(hi));
}

__global__ __launch_bounds__(256) void fill_all(const float* __restrict__ W0, const float* __restrict__ al0,
                                                const float* __restrict__ ar0,
                                                const float* __restrict__ W1, const float* __restrict__ al1,
                                                const float* __restrict__ ar1, const float* __restrict__ resW1,
                                                const float* __restrict__ W2, const float* __restrict__ al2,
                                                const float* __restrict__ ar2, const float* __restrict__ resW2,
                                                unsigned short* __restrict__ w0t, unsigned short* __restrict__ w1t,
                                                unsigned short* __restrict__ w2t) {
  const int n0 = 144 * 64, n1 = 272 * 128, n2 = 80 * 128;
  int t = blockIdx.x * 256 + threadIdx.x;
  if (t < n0) {
    pack_one(W0, al0, ar0, nullptr, w0t, 64, 144, 128, 4, 144, t);
  } else if (t < n0 + n1) {
    pack_one(W1, al1, ar1, resW1, w1t, 128, 272, 128, 4, 144, t - n0);
  } else if (t < n0 + n1 + n2) {
    pack_one(W2, al2, ar2, resW2, w2t, 128, 80, 32, 1, 48, t - n0 - n1);
  }
}

// ---------------- cmw[col] = invN * colsum @ (W_hi + W_lo)  (rank-1 PairNorm fold) ----------------
__global__ __launch_bounds__(256) void cmw_k(const float* __restrict__ colsum,
                                             const unsigned short* __restrict__ wt,
                                             float* __restrict__ cmw, int K, int M, float invN) {
  int c = blockIdx.x * 256 + threadIdx.x;
  if (c >= M) return;
  float s = 0.f;
  for (int k = 0; k < K; k++)
    s += colsum[k] * (bf2f(wt[c * K + k]) + bf2f(wt[(size_t)M * K + c * K + k]));
  cmw[c] = s * invN;
}

// ---------------- GEMM: A[N,K] @ Bt[M,K](bf16 hi+lo); epilogue: -cmw, route cols ----------------
// feat table written fp8-e4m3; el/er fp32; residual f16.
template <int K, int M, int R, int BF, int H, int RES0, bool AF32, bool CMW>
__global__ __launch_bounds__(256) void gemm_bf16(const void* __restrict__ Av,
                                                 const unsigned short* __restrict__ Bt,
                                                 const float* __restrict__ cmw,
                                                 unsigned char* __restrict__ feat8,
                                                 float* __restrict__ el, float* __restrict__ er,
                                                 unsigned short* __restrict__ resh, int nRowTiles) {
  int wv = (int)((blockIdx.x * blockDim.x + threadIdx.x) >> 6);
  int tile0 = wv * R;
  if (tile0 >= nRowTiles) return;
  int lane = threadIdx.x & 63;
  int r = lane & 15, q = lane >> 4;
  s8v afrag[R][K / 32];
#pragma unroll
  for (int rr = 0; rr < R; rr++) {
    if constexpr (AF32) {
      const float* arow = (const float*)Av + (size_t)((tile0 + rr) * 16 + r) * K + q * 8;
#pragma unroll
      for (int kk = 0; kk < K / 32; kk++) {
        s8v v;
#pragma unroll
        for (int j = 0; j < 8; j++) v[j] = (short)f2bf(arow[kk * 32 + j]);
        afrag[rr][kk] = v;
      }
    } else {
      const unsigned short* arow = (const unsigned short*)Av + (size_t)((tile0 + rr) * 16 + r) * K + q * 8;
#pragma unroll
      for (int kk = 0; kk < K / 32; kk++) afrag[rr][kk] = *(const s8v*)(arow + kk * 32);
    }
  }
#pragma unroll
  for (int ct = 0; ct < M / 16; ct++) {
    const unsigned short* brow = Bt + (size_t)(ct * 16 + r) * K + q * 8;
    s8v bhi[K / 32], blo[K / 32];
#pragma unroll
    for (int kk = 0; kk < K / 32; kk++) {
      bhi[kk] = *(const s8v*)(brow + kk * 32);
      blo[kk] = *(const s8v*)(brow + (size_t)M * K + kk * 32);
    }
    int col = ct * 16 + r;
    float cmwv = 0.f;
    if constexpr (CMW) cmwv = cmw[col];
#pragma unroll
    for (int rr = 0; rr < R; rr++) {
      f4v acc = {0.f, 0.f, 0.f, 0.f};
#pragma unroll
      for (int kk = 0; kk < K / 32; kk++) {
        acc = __builtin_amdgcn_mfma_f32_16x16x32_bf16(afrag[rr][kk], bhi[kk], acc, 0, 0, 0);
        acc = __builtin_amdgcn_mfma_f32_16x16x32_bf16(afrag[rr][kk], blo[kk], acc, 0, 0, 0);
      }
      int row0 = (tile0 + rr) * 16 + q * 4;
#pragma unroll
      for (int i = 0; i < 4; i++) {
        float v = acc[i] - cmwv;
        size_t row = (size_t)(row0 + i);
        if (col < BF) {
          feat8[row * BF + col] = f2fp8(v);
        } else if (col < BF + H) {
          el[row * H + (col - BF)] = v;
        } else if (col < BF + 2 * H) {
          er[row * H + (col - BF - H)] = v;
        } else if (RES0 < M && col >= RES0) {
          resh[row * (M - RES0) + (col - RES0)] = f2h(v);
        }
      }
    }
  }
}

// ---------------- fused single-pass aggregation H=4 (fp8 feat table) ----------------
// Phase A (slot x head): ex = exp(lrelu(el+er)), validity slot<deg, denom in regs.
// Phase B: 16 edges/chunk, whole wave per edge, lane owns dims {2l,2l+1} (2B fp8 load
// + 1 cvt_pk_f32_fp8 + 2 fma); 16 csr reads batched up-front (MLP).
template <int MODE>
__global__ __launch_bounds__(256) void aggregate4(const unsigned char* __restrict__ feat8,
                                                  const float* __restrict__ el4,
                                                  const float* __restrict__ er4,
                                                  const int* __restrict__ csr_src,
                                                  const int* __restrict__ rsp,
                                                  const int* __restrict__ counts,
                                                  const unsigned short* __restrict__ resh,
                                                  unsigned short* __restrict__ vbf,
                                                  float* __restrict__ rnrm, int Nn) {
  int n = (int)((blockIdx.x * blockDim.x + threadIdx.x) >> 6);
  if (n >= Nn) return;
  int lane = threadIdx.x & 63;
  int start = __builtin_amdgcn_readfirstlane(rsp[n]);
  int deg = __builtin_amdgcn_readfirstlane(counts[n]);
  int chunks = (deg + 15) >> 4;
  int slot = lane >> 2, h = lane & 3;
  float ern = er4[(size_t)n * 4 + h];
  int hl = lane >> 4;                        // head of lane's dims (dims 2l..2l+1)
  unsigned dby = (unsigned)lane << 1;        // byte offset into 128B fp8 row
  float a0 = 0.f, a1 = 0.f, dsum = 0.f;
  for (int c = 0; c < chunks; c++) {
    const int* csp = csr_src + start + (c << 4);
    // phase A: one (edge,head) per lane
    int sA = csp[slot];
    float exv = 0.f;
    if (((c << 4) + slot) < deg) {
      float e = el4[(size_t)sA * 4 + h] + ern;
      exv = __expf(fmaxf(e, 0.2f * e));
    }
    dsum += exv;
    // phase B: batch all 16 csr reads first (independent loads in flight)
    int sj[16];
#pragma unroll
    for (int j = 0; j < 16; j++) sj[j] = csp[j];
#pragma unroll
    for (int j = 0; j < 16; j++) {
      float aw = __shfl(exv, (j << 2) | hl);
      unsigned short u = *(const unsigned short*)(feat8 + (((unsigned)sj[j] << 7) + dby));
      f2v fv = __builtin_amdgcn_cvt_pk_f32_fp8((int)u, false);
      a0 = fmaf(fv[0], aw, a0);
      a1 = fmaf(fv[1], aw, a1);
    }
  }
  // per-head denominator totals: after butterfly, lane l holds head (l&3) total
#pragma unroll
  for (int off = 4; off < 64; off <<= 1) dsum += __shfl_xor(dsum, off);
  float inv = dsum > 0.f ? 1.f / dsum : 0.f;
  float invh = __shfl(inv, hl);
  float v0, v1;
  if (MODE == 1) {
    h2 rr = *(const h2*)(resh + (size_t)n * 128 + lane * 2);
    v0 = elu1(elu1(a0 * invh + (float)rr[0]));
    v1 = elu1(elu1(a1 * invh + (float)rr[1]));
  } else {
    v0 = elu1(a0 * invh);
    v1 = elu1(a1 * invh);
  }
  float ss = v0 * v0 + v1 * v1;
#pragma unroll
  for (int off = 1; off < 64; off <<= 1) ss += __shfl_xor(ss, off);
  float rn = sqrtf(1e-6f + ss);
  float ri = 1.f / rn;
  unsigned int pk = (unsigned int)f2bf(v0 * ri) | ((unsigned int)f2bf(v1 * ri) << 16);
  *(unsigned int*)((char*)vbf + ((size_t)n << 8) + (lane << 2)) = pk;
  if (lane == 0) rnrm[n] = rn;
}

// ---------------- fused single-pass aggregation H=1 (layer 2, fp8 table 3.2MB: L2-resident) ----------------
__global__ __launch_bounds__(256) void aggregate1(const unsigned char* __restrict__ feat8,
                                                  const float* __restrict__ el1,
                                                  const float* __restrict__ er1,
                                                  const int* __restrict__ csr_src,
                                                  const int* __restrict__ rsp,
                                                  const int* __restrict__ counts,
                                                  const unsigned short* __restrict__ res2h,
                                                  float* __restrict__ out2, int Nn) {
  int n = (int)((blockIdx.x * blockDim.x + threadIdx.x) >> 6);
  if (n >= Nn) return;
  int lane = threadIdx.x & 63;
  int start = __builtin_amdgcn_readfirstlane(rsp[n]);
  int deg = __builtin_amdgcn_readfirstlane(counts[n]);
  int chunks = (deg + 15) >> 4;
  int l16 = lane & 15;
  float ern = er1[n];
  int g = lane >> 3;                          // 8 edge groups (2 edges each per chunk)
  unsigned dofs4 = (unsigned)(lane & 7) << 2; // byte offset into 32B fp8 row
  f4v acc = {0.f, 0.f, 0.f, 0.f};
  float dsum = 0.f;
  for (int c = 0; c < chunks; c++) {
    const int* csp = csr_src + start + (c << 4);
    int sA = csp[l16];
    float exv = 0.f;
    if (((c << 4) + l16) < deg) exv = __expf(lrelu(el1[sA] + ern));
    dsum += exv;
#pragma unroll
    for (int t = 0; t < 2; t++) {
      int j = (t << 3) + g;
      int sj = __shfl(sA, j);
      float aw = __shfl(exv, j);
      unsigned int u = *(const unsigned int*)(feat8 + (((unsigned)sj << 5) + dofs4));
      f2v fa = __builtin_amdgcn_cvt_pk_f32_fp8((int)u, false);
      f2v fb = __builtin_amdgcn_cvt_pk_f32_fp8((int)u, true);
      acc[0] = fmaf(fa[0], aw, acc[0]);
      acc[1] = fmaf(fa[1], aw, acc[1]);
      acc[2] = fmaf(fb[0], aw, acc[2]);
      acc[3] = fmaf(fb[1], aw, acc[3]);
    }
  }
#pragma unroll
  for (int off = 1; off < 16; off <<= 1) dsum += __shfl_xor(dsum, off);
  float inv = dsum > 0.f ? 1.f / dsum : 0.f;
#pragma unroll
  for (int off = 8; off < 64; off <<= 1) {
    acc[0] += __shfl_xor(acc[0], off);
    acc[1] += __shfl_xor(acc[1], off);
    acc[2] += __shfl_xor(acc[2], off);
    acc[3] += __shfl_xor(acc[3], off);
  }
  if (lane < 8) {
    h4 rr = *(const h4*)(res2h + (size_t)n * 32 + (lane << 2));
    float4 o;
    o.x = acc[0] * inv + (float)rr[0];
    o.y = acc[1] * inv + (float)rr[1];
    o.z = acc[2] * inv + (float)rr[2];
    o.w = acc[3] * inv + (float)rr[3];
    *(float4*)(out2 + (size_t)n * 32 + (lane << 2)) = o;
  }
}

// ---------------- colsum of raw v = vbf * rnrm (PairNorm colmean numerator) ----------------
__global__ __launch_bounds__(256) void colsum_k(const unsigned short* __restrict__ vbf,
                                                const float* __restrict__ rnrm,
                                                float* __restrict__ colsum, int Nn) {
  __shared__ float ls[256];
  int tid = threadIdx.x;
  int c = tid & 127, rsub = tid >> 7;
  float cs = 0.f;
  for (int r = blockIdx.x * 2 + rsub; r < Nn; r += gridDim.x * 2)
    cs += bf2f(vbf[(size_t)r * 128 + c]) * rnrm[r];
  ls[tid] = cs;
  __syncthreads();
  if (tid < 128) atomicAdd(&colsum[tid], ls[tid] + ls[tid + 128]);
}

// ---------------- final: mean over nodes of out2 ----------------
__global__ __launch_bounds__(256) void final_reduce(const float* __restrict__ out2,
                                                    float* __restrict__ outsum, int Nn) {
  __shared__ float ls[32];
  if (threadIdx.x < 32) ls[threadIdx.x] = 0.f;
  __syncthreads();
  int d = threadIdx.x & 31, rl = threadIdx.x >> 5;
  float acc = 0.f;
  for (int n = blockIdx.x * 8 + rl; n < Nn; n += gridDim.x * 8)
    acc += out2[(size_t)n * 32 + d];
  atomicAdd(&ls[d], acc);
  __syncthreads();
  if (threadIdx.x < 32) atomicAdd(&outsum[threadIdx.x], ls[threadIdx.x]);
}

__global__ void finalize_k(const float* __restrict__ outsum, float* __restrict__ out, float invN) {
  int t = threadIdx.x;
  if (t < 32) out[t] = outsum[t] * invN;
}

// ---------------- launcher ----------------
extern "C" void kernel_launch(void* const* d_in, const int* in_sizes, int n_in,
                              void* d_out, int out_size, void* d_ws, size_t ws_size,
                              hipStream_t stream) {
  const float* x     = (const float*)d_in[0];
  const int*   src   = (const int*)d_in[1];
  const int*   dst   = (const int*)d_in[2];
  const float* W0    = (const float*)d_in[3];
  const float* al0   = (const float*)d_in[4];
  const float* ar0   = (const float*)d_in[5];
  const float* W1    = (const float*)d_in[6];
  const float* al1   = (const float*)d_in[7];
  const float* ar1   = (const float*)d_in[8];
  const float* resW1 = (const float*)d_in[9];
  const float* W2    = (const float*)d_in[10];
  const float* al2   = (const float*)d_in[11];
  const float* ar2   = (const float*)d_in[12];
  const float* resW2 = (const float*)d_in[13];
  const int N = in_sizes[0] / 64;   // 100000
  const int E = in_sizes[1];        // 1600000
  const float invN = 1.f / (float)N;
  const int Emax = E + 15 * N + 1024;   // upper bound on padded slot count + margin
  int shift = 0;
  while (((unsigned)(N - 1) >> shift) > 7u) shift++;   // 8 dst-range buckets

  char* p = (char*)d_ws;
  auto alloc = [&](size_t bytes) { char* r = p; p += (bytes + 255) & ~(size_t)255; return r; };

  // zero-initialized region
  char* zbase = p;
  int*   counts  = (int*)alloc((size_t)4 * N);
  float* colsumA = (float*)alloc(512);
  float* colsumB = (float*)alloc(512);
  float* outsum  = (float*)alloc(128);
  size_t zbytes = (size_t)(p - zbase);

  int* rsp    = (int*)alloc((size_t)4 * N);     // padded row starts
  int* cursor = (int*)alloc((size_t)4 * N);
  int* bsum   = (int*)alloc(512);
  int* csr_src = (int*)alloc((size_t)4 * Emax);     // memset 0: pads -> node 0, alpha 0
  unsigned char*  feat8 = (unsigned char*)alloc((size_t)N * 128);     // fp8 gather table
  unsigned short* vbf   = (unsigned short*)alloc((size_t)2 * N * 128);
  unsigned short* resh  = (unsigned short*)alloc((size_t)2 * N * 128);  // f16 residuals
  unsigned short* w0t = (unsigned short*)alloc((size_t)2 * 2 * 144 * 64);
  unsigned short* w1t = (unsigned short*)alloc((size_t)2 * 2 * 272 * 128);
  unsigned short* w2t = (unsigned short*)alloc((size_t)2 * 2 * 80 * 128);
  float* el4  = (float*)alloc((size_t)16 * N);
  float* er4  = (float*)alloc((size_t)16 * N);
  float* rnrm = (float*)alloc((size_t)4 * N);
  float* cmw1 = (float*)alloc(4 * 272);
  float* cmw2 = (float*)alloc(4 * 80);
  float* out2 = (float*)alloc((size_t)4 * N * 32);   // layer-2 output [N][32]

  hipMemsetAsync(zbase, 0, zbytes, stream);
  hipMemsetAsync(csr_src, 0, (size_t)4 * Emax, stream);

  // CSR build (padded)
  int eb = (E + 255) / 256;
  int nb1024 = (N + 1023) / 1024;
  hist_k<<<eb, 256, 0, stream>>>(dst, counts, E);
  scan1<<<nb1024, 256, 0, stream>>>(counts, rsp, bsum, N);
  scan2<<<1, 128, 0, stream>>>(bsum, nb1024);
  scan3<<<(N + 255) / 256, 256, 0, stream>>>(rsp, bsum, cursor, N);
  pscatter_k<<<1024, 256, 0, stream>>>(src, dst, cursor, csr_src, E, shift);

  // weights: [W | W@al | W@ar | pad | resW] transposed, bf16 hi+lo — one launch
  const int packTot = 144 * 64 + 272 * 128 + 80 * 128;
  fill_all<<<(packTot + 255) / 256, 256, 0, stream>>>(W0, al0, ar0, W1, al1, ar1, resW1,
                                                      W2, al2, ar2, resW2, w0t, w1t, w2t);

  const int rowTiles = N / 16;                  // 6250, divisible by R=5
  const int gblocks = (rowTiles / 5 + 3) / 4;   // 1250 waves, 4/block
  const int aggblocks = (N + 3) / 4;            // wave per node

  // Layer 0 (A = x fp32, no colmean fold)
  gemm_bf16<64, 144, 5, 128, 4, 144, true, false><<<gblocks, 256, 0, stream>>>(
      x, w0t, nullptr, feat8, el4, er4, nullptr, rowTiles);
  aggregate4<0><<<aggblocks, 256, 0, stream>>>(feat8, el4, er4, csr_src, rsp, counts, nullptr, vbf, rnrm, N);
  colsum_k<<<512, 256, 0, stream>>>(vbf, rnrm, colsumA, N);
  cmw_k<<<2, 256, 0, stream>>>(colsumA, w1t, cmw1, 128, 272, invN);

  // Layer 1 (A = vbf, colmean folded via cmw1)
  gemm_bf16<128, 272, 5, 128, 4, 144, false, true><<<gblocks, 256, 0, stream>>>(
      vbf, w1t, cmw1, feat8, el4, er4, resh, rowTiles);
  aggregate4<1><<<aggblocks, 256, 0, stream>>>(feat8, el4, er4, csr_src, rsp, counts, resh, vbf, rnrm, N);
  colsum_k<<<512, 256, 0, stream>>>(vbf, rnrm, colsumB, N);
  cmw_k<<<1, 256, 0, stream>>>(colsumB, w2t, cmw2, 128, 80, invN);

  // Layer 2 (A = vbf, colmean folded via cmw2)
  gemm_bf16<128, 80, 5, 32, 1, 48, false, true><<<gblocks, 256, 0, stream>>>(
      vbf, w2t, cmw2, feat8, el4, er4, resh, rowTiles);
  aggregate1<<<aggblocks, 256, 0, stream>>>(feat8, el4, er4, csr_src, rsp, counts, resh, out2, N);
  final_reduce<<<512, 256, 0, stream>>>(out2, outsum, N);
  finalize_k<<<1, 64, 0, stream>>>(outsum, (float*)d_out, invN);
}

// Round 12
// 619.596 us; speedup vs baseline: 1.0822x; 1.0402x over previous
//
#include <hip/hip_runtime.h>

// GAT 3-layer forward on MI355X — round 12.
// vs round 11 (best, 644.5us): CSR build replaced by a 3-pass counting sort with
// single-owner cache lines. R11's pscatter wrote 81MB for a 13MB array (6x write
// amplification) because blocks on different non-coherent XCD L2s appended into the
// same 64B lines. Now: per-(block,bucket) histogram -> exclusive scan -> private-
// segment bucket scatter (LDS cursors, no global atomics) -> per-bucket final scatter
// (one block per 256-node bucket, ~17KB private csr region, LDS cursors).

typedef __attribute__((ext_vector_type(8))) short s8v;
typedef __attribute__((ext_vector_type(4))) float f4v;
typedef __attribute__((ext_vector_type(2))) float f2v;
typedef __attribute__((ext_vector_type(2))) _Float16 h2;
typedef __attribute__((ext_vector_type(4))) _Float16 h4;

__device__ __forceinline__ unsigned short f2bf(float f) {
  unsigned int x = __float_as_uint(f);
  x += 0x7fffu + ((x >> 16) & 1u);          // RTNE
  return (unsigned short)(x >> 16);
}
__device__ __forceinline__ float bf2f(unsigned short u) {
  return __uint_as_float(((unsigned int)u) << 16);
}
__device__ __forceinline__ unsigned short f2h(float f) {
  _Float16 h = (_Float16)f;
  return __builtin_bit_cast(unsigned short, h);
}
__device__ __forceinline__ unsigned char f2fp8(float v) {
  return (unsigned char)(__builtin_amdgcn_cvt_pk_fp8_f32(v, v, 0, false) & 0xff);
}
__device__ __forceinline__ float lrelu(float x) { return fmaxf(x, 0.2f * x); }
__device__ __forceinline__ float elu1(float x) { return x > 0.f ? x : expm1f(x); }

// ---------------- per-node degree histogram (for rsp) ----------------
__global__ __launch_bounds__(256) void hist_k(const int* __restrict__ dst, int* __restrict__ counts, int E) {
  int t = blockIdx.x * 256 + threadIdx.x;
  if (t < E) atomicAdd(&counts[dst[t]], 1);
}

// scan1: exclusive prefix over counts ROUNDED UP to 16 (padded row starts)
__global__ __launch_bounds__(256) void scan1(const int* __restrict__ counts, int* __restrict__ rsp,
                                             int* __restrict__ bsum, int Nn) {
  __shared__ int s[256];
  int t = threadIdx.x;
  int base = blockIdx.x * 1024 + t * 4;
  int v0 = (base + 0 < Nn) ? ((counts[base + 0] + 15) & ~15) : 0;
  int v1 = (base + 1 < Nn) ? ((counts[base + 1] + 15) & ~15) : 0;
  int v2 = (base + 2 < Nn) ? ((counts[base + 2] + 15) & ~15) : 0;
  int v3 = (base + 3 < Nn) ? ((counts[base + 3] + 15) & ~15) : 0;
  s[t] = v0 + v1 + v2 + v3;
  __syncthreads();
  for (int off = 1; off < 256; off <<= 1) {
    int xv = (t >= off) ? s[t - off] : 0;
    __syncthreads();
    s[t] += xv;
    __syncthreads();
  }
  int excl = t ? s[t - 1] : 0;
  if (t == 255) bsum[blockIdx.x] = s[255];
  if (base + 0 < Nn) { rsp[base + 0] = excl; excl += v0; }
  if (base + 1 < Nn) { rsp[base + 1] = excl; excl += v1; }
  if (base + 2 < Nn) { rsp[base + 2] = excl; excl += v2; }
  if (base + 3 < Nn) { rsp[base + 3] = excl; }
}

// pscan1: plain (no rounding) exclusive prefix — for the bucket-segment table
__global__ __launch_bounds__(256) void pscan1(const int* __restrict__ in, int* __restrict__ out,
                                              int* __restrict__ bsum, int Nn) {
  __shared__ int s[256];
  int t = threadIdx.x;
  int base = blockIdx.x * 1024 + t * 4;
  int v0 = (base + 0 < Nn) ? in[base + 0] : 0;
  int v1 = (base + 1 < Nn) ? in[base + 1] : 0;
  int v2 = (base + 2 < Nn) ? in[base + 2] : 0;
  int v3 = (base + 3 < Nn) ? in[base + 3] : 0;
  s[t] = v0 + v1 + v2 + v3;
  __syncthreads();
  for (int off = 1; off < 256; off <<= 1) {
    int xv = (t >= off) ? s[t - off] : 0;
    __syncthreads();
    s[t] += xv;
    __syncthreads();
  }
  int excl = t ? s[t - 1] : 0;
  if (t == 255) bsum[blockIdx.x] = s[255];
  if (base + 0 < Nn) { out[base + 0] = excl; excl += v0; }
  if (base + 1 < Nn) { out[base + 1] = excl; excl += v1; }
  if (base + 2 < Nn) { out[base + 2] = excl; excl += v2; }
  if (base + 3 < Nn) { out[base + 3] = excl; }
}

__global__ __launch_bounds__(128) void scan2(int* __restrict__ bsum, int nb) {
  __shared__ int s[128];
  int t = threadIdx.x;
  s[t] = (t < nb) ? bsum[t] : 0;
  __syncthreads();
  for (int off = 1; off < 128; off <<= 1) {
    int xv = (t >= off) ? s[t - off] : 0;
    __syncthreads();
    s[t] += xv;
    __syncthreads();
  }
  if (t < nb) bsum[t] = t ? s[t - 1] : 0;
}

__global__ __launch_bounds__(256) void scan3(int* __restrict__ arr, const int* __restrict__ bsum, int Nn) {
  int t = blockIdx.x * 256 + threadIdx.x;
  if (t < Nn) arr[t] += bsum[t >> 10];
}

// ---------------- pass 1: per-(block,bucket) histogram; bucket = dst>>8 ----------------
__global__ __launch_bounds__(256) void bhist_k(const int* __restrict__ dst, int* __restrict__ bhist,
                                               int E, int NB, int chunk) {
  __shared__ int h[512];
  for (int b = threadIdx.x; b < NB; b += 256) h[b] = 0;
  __syncthreads();
  int e0 = blockIdx.x * chunk;
  int e1 = min(E, e0 + chunk);
  for (int e = e0 + threadIdx.x; e < e1; e += 256) atomicAdd(&h[dst[e] >> 8], 1);
  __syncthreads();
  for (int b = threadIdx.x; b < NB; b += 256)
    bhist[(size_t)b * gridDim.x + blockIdx.x] = h[b];
}

// ---------------- pass 2: scatter edges into private (block,bucket) segments ----------------
__global__ __launch_bounds__(256) void bscatter_k(const int* __restrict__ src, const int* __restrict__ dst,
                                                  const int* __restrict__ seg, int2* __restrict__ ebuf,
                                                  int E, int NB, int chunk) {
  __shared__ int cur[512];
  for (int b = threadIdx.x; b < NB; b += 256)
    cur[b] = seg[(size_t)b * gridDim.x + blockIdx.x];
  __syncthreads();
  int e0 = blockIdx.x * chunk;
  int e1 = min(E, e0 + chunk);
  for (int e = e0 + threadIdx.x; e < e1; e += 256) {
    int d = dst[e];
    int pos = atomicAdd(&cur[d >> 8], 1);
    int2 v; v.x = src[e]; v.y = d;
    ebuf[pos] = v;
  }
}

// ---------------- pass 3: per-bucket final scatter (one block per 256-node bucket) ----------------
__global__ __launch_bounds__(256) void fscatter_k(const int2* __restrict__ ebuf, const int* __restrict__ seg,
                                                  const int* __restrict__ rsp, int* __restrict__ csr_src,
                                                  int E, int NB, int P2B, int Nn) {
  __shared__ int cur[256];
  int b = blockIdx.x;
  int node0 = b << 8;
  int node = node0 + threadIdx.x;
  if (node < Nn) cur[threadIdx.x] = rsp[node];
  __syncthreads();
  int bstart = seg[(size_t)b * P2B];
  int bend = (b + 1 < NB) ? seg[(size_t)(b + 1) * P2B] : E;
  for (int e = bstart + threadIdx.x; e < bend; e += 256) {
    int2 sd = ebuf[e];
    int pos = atomicAdd(&cur[sd.y - node0], 1);
    csr_src[pos] = sd.x;
  }
}

// ---------------- fused weight pack (all 3 layers, one launch) ----------------
__device__ __forceinline__ void pack_one(const float* W, const float* al, const float* ar,
                                         const float* resW, unsigned short* out,
                                         int K, int M, int BF, int H, int RES0, int t) {
  int c = t / K, k = t - c * K;
  float v = 0.f;
  if (c < BF) {
    v = W[k * BF + c];
  } else if (c < BF + H) {
    int h = c - BF;
    float s = 0.f;
    for (int d = 0; d < 32; d++) s += W[k * BF + h * 32 + d] * al[h * 32 + d];
    v = s;
  } else if (c < BF + 2 * H) {
    int h = c - BF - H;
    float s = 0.f;
    for (int d = 0; d < 32; d++) s += W[k * BF + h * 32 + d] * ar[h * 32 + d];
    v = s;
  } else if (c >= RES0) {
    v = resW[k * (M - RES0) + (c - RES0)];
  }
  unsigned short hi = f2bf(v);
  out[c * K + k] = hi;
  out[M * K + c * K + k] = f2bf(v - bf2f(hi));
}

__global__ __launch_bounds__(256) void fill_all(const float* __restrict__ W0, const float* __restrict__ al0,
                                                const float* __restrict__ ar0,
                                                const float* __restrict__ W1, const float* __restrict__ al1,
                                                const float* __restrict__ ar1, const float* __restrict__ resW1,
                                                const float* __restrict__ W2, const float* __restrict__ al2,
                                                const float* __restrict__ ar2, const float* __restrict__ resW2,
                                                unsigned short* __restrict__ w0t, unsigned short* __restrict__ w1t,
                                                unsigned short* __restrict__ w2t) {
  const int n0 = 144 * 64, n1 = 272 * 128, n2 = 80 * 128;
  int t = blockIdx.x * 256 + threadIdx.x;
  if (t < n0) {
    pack_one(W0, al0, ar0, nullptr, w0t, 64, 144, 128, 4, 144, t);
  } else if (t < n0 + n1) {
    pack_one(W1, al1, ar1, resW1, w1t, 128, 272, 128, 4, 144, t - n0);
  } else if (t < n0 + n1 + n2) {
    pack_one(W2, al2, ar2, resW2, w2t, 128, 80, 32, 1, 48, t - n0 - n1);
  }
}

// ---------------- cmw[col] = invN * colsum @ (W_hi + W_lo)  (rank-1 PairNorm fold) ----------------
__global__ __launch_bounds__(256) void cmw_k(const float* __restrict__ colsum,
                                             const unsigned short* __restrict__ wt,
                                             float* __restrict__ cmw, int K, int M, float invN) {
  int c = blockIdx.x * 256 + threadIdx.x;
  if (c >= M) return;
  float s = 0.f;
  for (int k = 0; k < K; k++)
    s += colsum[k] * (bf2f(wt[c * K + k]) + bf2f(wt[(size_t)M * K + c * K + k]));
  cmw[c] = s * invN;
}

// ---------------- GEMM: A[N,K] @ Bt[M,K](bf16 hi+lo); epilogue: -cmw, route cols ----------------
template <int K, int M, int R, int BF, int H, int RES0, bool AF32, bool CMW>
__global__ __launch_bounds__(256) void gemm_bf16(const void* __restrict__ Av,
                                                 const unsigned short* __restrict__ Bt,
                                                 const float* __restrict__ cmw,
                                                 unsigned char* __restrict__ feat8,
                                                 float* __restrict__ el, float* __restrict__ er,
                                                 unsigned short* __restrict__ resh, int nRowTiles) {
  int wv = (int)((blockIdx.x * blockDim.x + threadIdx.x) >> 6);
  int tile0 = wv * R;
  if (tile0 >= nRowTiles) return;
  int lane = threadIdx.x & 63;
  int r = lane & 15, q = lane >> 4;
  s8v afrag[R][K / 32];
#pragma unroll
  for (int rr = 0; rr < R; rr++) {
    if constexpr (AF32) {
      const float* arow = (const float*)Av + (size_t)((tile0 + rr) * 16 + r) * K + q * 8;
#pragma unroll
      for (int kk = 0; kk < K / 32; kk++) {
        s8v v;
#pragma unroll
        for (int j = 0; j < 8; j++) v[j] = (short)f2bf(arow[kk * 32 + j]);
        afrag[rr][kk] = v;
      }
    } else {
      const unsigned short* arow = (const unsigned short*)Av + (size_t)((tile0 + rr) * 16 + r) * K + q * 8;
#pragma unroll
      for (int kk = 0; kk < K / 32; kk++) afrag[rr][kk] = *(const s8v*)(arow + kk * 32);
    }
  }
#pragma unroll
  for (int ct = 0; ct < M / 16; ct++) {
    const unsigned short* brow = Bt + (size_t)(ct * 16 + r) * K + q * 8;
    s8v bhi[K / 32], blo[K / 32];
#pragma unroll
    for (int kk = 0; kk < K / 32; kk++) {
      bhi[kk] = *(const s8v*)(brow + kk * 32);
      blo[kk] = *(const s8v*)(brow + (size_t)M * K + kk * 32);
    }
    int col = ct * 16 + r;
    float cmwv = 0.f;
    if constexpr (CMW) cmwv = cmw[col];
#pragma unroll
    for (int rr = 0; rr < R; rr++) {
      f4v acc = {0.f, 0.f, 0.f, 0.f};
#pragma unroll
      for (int kk = 0; kk < K / 32; kk++) {
        acc = __builtin_amdgcn_mfma_f32_16x16x32_bf16(afrag[rr][kk], bhi[kk], acc, 0, 0, 0);
        acc = __builtin_amdgcn_mfma_f32_16x16x32_bf16(afrag[rr][kk], blo[kk], acc, 0, 0, 0);
      }
      int row0 = (tile0 + rr) * 16 + q * 4;
#pragma unroll
      for (int i = 0; i < 4; i++) {
        float v = acc[i] - cmwv;
        size_t row = (size_t)(row0 + i);
        if (col < BF) {
          feat8[row * BF + col] = f2fp8(v);
        } else if (col < BF + H) {
          el[row * H + (col - BF)] = v;
        } else if (col < BF + 2 * H) {
          er[row * H + (col - BF - H)] = v;
        } else if (RES0 < M && col >= RES0) {
          resh[row * (M - RES0) + (col - RES0)] = f2h(v);
        }
      }
    }
  }
}

// ---------------- fused single-pass aggregation H=4 (fp8 feat table) ----------------
template <int MODE>
__global__ __launch_bounds__(256) void aggregate4(const unsigned char* __restrict__ feat8,
                                                  const float* __restrict__ el4,
                                                  const float* __restrict__ er4,
                                                  const int* __restrict__ csr_src,
                                                  const int* __restrict__ rsp,
                                                  const int* __restrict__ counts,
                                                  const unsigned short* __restrict__ resh,
                                                  unsigned short* __restrict__ vbf,
                                                  float* __restrict__ rnrm, int Nn) {
  int n = (int)((blockIdx.x * blockDim.x + threadIdx.x) >> 6);
  if (n >= Nn) return;
  int lane = threadIdx.x & 63;
  int start = __builtin_amdgcn_readfirstlane(rsp[n]);
  int deg = __builtin_amdgcn_readfirstlane(counts[n]);
  int chunks = (deg + 15) >> 4;
  int slot = lane >> 2, h = lane & 3;
  float ern = er4[(size_t)n * 4 + h];
  int hl = lane >> 4;                        // head of lane's dims (dims 2l..2l+1)
  unsigned dby = (unsigned)lane << 1;        // byte offset into 128B fp8 row
  float a0 = 0.f, a1 = 0.f, dsum = 0.f;
  for (int c = 0; c < chunks; c++) {
    const int* csp = csr_src + start + (c << 4);
    // phase A: one (edge,head) per lane
    int sA = csp[slot];
    float exv = 0.f;
    if (((c << 4) + slot) < deg) {
      float e = el4[(size_t)sA * 4 + h] + ern;
      exv = __expf(fmaxf(e, 0.2f * e));
    }
    dsum += exv;
    // phase B: batch all 16 csr reads first (independent loads in flight)
    int sj[16];
#pragma unroll
    for (int j = 0; j < 16; j++) sj[j] = csp[j];
#pragma unroll
    for (int j = 0; j < 16; j++) {
      float aw = __shfl(exv, (j << 2) | hl);
      unsigned short u = *(const unsigned short*)(feat8 + (((unsigned)sj[j] << 7) + dby));
      f2v fv = __builtin_amdgcn_cvt_pk_f32_fp8((int)u, false);
      a0 = fmaf(fv[0], aw, a0);
      a1 = fmaf(fv[1], aw, a1);
    }
  }
  // per-head denominator totals: after butterfly, lane l holds head (l&3) total
#pragma unroll
  for (int off = 4; off < 64; off <<= 1) dsum += __shfl_xor(dsum, off);
  float inv = dsum > 0.f ? 1.f / dsum : 0.f;
  float invh = __shfl(inv, hl);
  float v0, v1;
  if (MODE == 1) {
    h2 rr = *(const h2*)(resh + (size_t)n * 128 + lane * 2);
    v0 = elu1(elu1(a0 * invh + (float)rr[0]));
    v1 = elu1(elu1(a1 * invh + (float)rr[1]));
  } else {
    v0 = elu1(a0 * invh);
    v1 = elu1(a1 * invh);
  }
  float ss = v0 * v0 + v1 * v1;
#pragma unroll
  for (int off = 1; off < 64; off <<= 1) ss += __shfl_xor(ss, off);
  float rn = sqrtf(1e-6f + ss);
  float ri = 1.f / rn;
  unsigned int pk = (unsigned int)f2bf(v0 * ri) | ((unsigned int)f2bf(v1 * ri) << 16);
  *(unsigned int*)((char*)vbf + ((size_t)n << 8) + (lane << 2)) = pk;
  if (lane == 0) rnrm[n] = rn;
}

// ---------------- fused single-pass aggregation H=1 (layer 2, fp8 table) ----------------
__global__ __launch_bounds__(256) void aggregate1(const unsigned char* __restrict__ feat8,
                                                  const float* __restrict__ el1,
                                                  const float* __restrict__ er1,
                                                  const int* __restrict__ csr_src,
                                                  const int* __restrict__ rsp,
                                                  const int* __restrict__ counts,
                                                  const unsigned short* __restrict__ res2h,
                                                  float* __restrict__ out2, int Nn) {
  int n = (int)((blockIdx.x * blockDim.x + threadIdx.x) >> 6);
  if (n >= Nn) return;
  int lane = threadIdx.x & 63;
  int start = __builtin_amdgcn_readfirstlane(rsp[n]);
  int deg = __builtin_amdgcn_readfirstlane(counts[n]);
  int chunks = (deg + 15) >> 4;
  int l16 = lane & 15;
  float ern = er1[n];
  int g = lane >> 3;                          // 8 edge groups (2 edges each per chunk)
  unsigned dofs4 = (unsigned)(lane & 7) << 2; // byte offset into 32B fp8 row
  f4v acc = {0.f, 0.f, 0.f, 0.f};
  float dsum = 0.f;
  for (int c = 0; c < chunks; c++) {
    const int* csp = csr_src + start + (c << 4);
    int sA = csp[l16];
    float exv = 0.f;
    if (((c << 4) + l16) < deg) exv = __expf(lrelu(el1[sA] + ern));
    dsum += exv;
#pragma unroll
    for (int t = 0; t < 2; t++) {
      int j = (t << 3) + g;
      int sj = __shfl(sA, j);
      float aw = __shfl(exv, j);
      unsigned int u = *(const unsigned int*)(feat8 + (((unsigned)sj << 5) + dofs4));
      f2v fa = __builtin_amdgcn_cvt_pk_f32_fp8((int)u, false);
      f2v fb = __builtin_amdgcn_cvt_pk_f32_fp8((int)u, true);
      acc[0] = fmaf(fa[0], aw, acc[0]);
      acc[1] = fmaf(fa[1], aw, acc[1]);
      acc[2] = fmaf(fb[0], aw, acc[2]);
      acc[3] = fmaf(fb[1], aw, acc[3]);
    }
  }
#pragma unroll
  for (int off = 1; off < 16; off <<= 1) dsum += __shfl_xor(dsum, off);
  float inv = dsum > 0.f ? 1.f / dsum : 0.f;
#pragma unroll
  for (int off = 8; off < 64; off <<= 1) {
    acc[0] += __shfl_xor(acc[0], off);
    acc[1] += __shfl_xor(acc[1], off);
    acc[2] += __shfl_xor(acc[2], off);
    acc[3] += __shfl_xor(acc[3], off);
  }
  if (lane < 8) {
    h4 rr = *(const h4*)(res2h + (size_t)n * 32 + (lane << 2));
    float4 o;
    o.x = acc[0] * inv + (float)rr[0];
    o.y = acc[1] * inv + (float)rr[1];
    o.z = acc[2] * inv + (float)rr[2];
    o.w = acc[3] * inv + (float)rr[3];
    *(float4*)(out2 + (size_t)n * 32 + (lane << 2)) = o;
  }
}

// ---------------- colsum of raw v = vbf * rnrm (PairNorm colmean numerator) ----------------
__global__ __launch_bounds__(256) void colsum_k(const unsigned short* __restrict__ vbf,
                                                const float* __restrict__ rnrm,
                                                float* __restrict__ colsum, int Nn) {
  __shared__ float ls[256];
  int tid = threadIdx.x;
  int c = tid & 127, rsub = tid >> 7;
  float cs = 0.f;
  for (int r = blockIdx.x * 2 + rsub; r < Nn; r += gridDim.x * 2)
    cs += bf2f(vbf[(size_t)r * 128 + c]) * rnrm[r];
  ls[tid] = cs;
  __syncthreads();
  if (tid < 128) atomicAdd(&colsum[tid], ls[tid] + ls[tid + 128]);
}

// ---------------- final: mean over nodes of out2 ----------------
__global__ __launch_bounds__(256) void final_reduce(const float* __restrict__ out2,
                                                    float* __restrict__ outsum, int Nn) {
  __shared__ float ls[32];
  if (threadIdx.x < 32) ls[threadIdx.x] = 0.f;
  __syncthreads();
  int d = threadIdx.x & 31, rl = threadIdx.x >> 5;
  float acc = 0.f;
  for (int n = blockIdx.x * 8 + rl; n < Nn; n += gridDim.x * 8)
    acc += out2[(size_t)n * 32 + d];
  atomicAdd(&ls[d], acc);
  __syncthreads();
  if (threadIdx.x < 32) atomicAdd(&outsum[threadIdx.x], ls[threadIdx.x]);
}

__global__ void finalize_k(const float* __restrict__ outsum, float* __restrict__ out, float invN) {
  int t = threadIdx.x;
  if (t < 32) out[t] = outsum[t] * invN;
}

// ---------------- launcher ----------------
extern "C" void kernel_launch(void* const* d_in, const int* in_sizes, int n_in,
                              void* d_out, int out_size, void* d_ws, size_t ws_size,
                              hipStream_t stream) {
  const float* x     = (const float*)d_in[0];
  const int*   src   = (const int*)d_in[1];
  const int*   dst   = (const int*)d_in[2];
  const float* W0    = (const float*)d_in[3];
  const float* al0   = (const float*)d_in[4];
  const float* ar0   = (const float*)d_in[5];
  const float* W1    = (const float*)d_in[6];
  const float* al1   = (const float*)d_in[7];
  const float* ar1   = (const float*)d_in[8];
  const float* resW1 = (const float*)d_in[9];
  const float* W2    = (const float*)d_in[10];
  const float* al2   = (const float*)d_in[11];
  const float* ar2   = (const float*)d_in[12];
  const float* resW2 = (const float*)d_in[13];
  const int N = in_sizes[0] / 64;   // 100000
  const int E = in_sizes[1];        // 1600000
  const float invN = 1.f / (float)N;
  const int Emax = E + 15 * N + 1024;   // upper bound on padded slot count + margin
  const int NB = (N + 255) >> 8;        // dst buckets of 256 nodes (391)
  const int P2B = 256;                  // pass-2 block count
  const int chunk = (E + P2B - 1) / P2B;
  const int segN = NB * P2B;            // bucket-major segment table length

  char* p = (char*)d_ws;
  auto alloc = [&](size_t bytes) { char* r = p; p += (bytes + 255) & ~(size_t)255; return r; };

  // zero-initialized region
  char* zbase = p;
  int*   counts  = (int*)alloc((size_t)4 * N);
  float* colsumA = (float*)alloc(512);
  float* colsumB = (float*)alloc(512);
  float* outsum  = (float*)alloc(128);
  size_t zbytes = (size_t)(p - zbase);

  int* rsp   = (int*)alloc((size_t)4 * N);      // padded row starts
  int* bsum  = (int*)alloc(512);
  int* bhist = (int*)alloc((size_t)4 * segN);   // per-(bucket,block) counts -> seg (scanned in place)
  int* bsum2 = (int*)alloc(512);
  int2* ebuf = (int2*)alloc((size_t)8 * E);     // bucketed {src,dst}
  int* csr_src = (int*)alloc((size_t)4 * Emax); // memset 0: pads -> node 0, alpha 0
  unsigned char*  feat8 = (unsigned char*)alloc((size_t)N * 128);     // fp8 gather table
  unsigned short* vbf   = (unsigned short*)alloc((size_t)2 * N * 128);
  unsigned short* resh  = (unsigned short*)alloc((size_t)2 * N * 128);  // f16 residuals
  unsigned short* w0t = (unsigned short*)alloc((size_t)2 * 2 * 144 * 64);
  unsigned short* w1t = (unsigned short*)alloc((size_t)2 * 2 * 272 * 128);
  unsigned short* w2t = (unsigned short*)alloc((size_t)2 * 2 * 80 * 128);
  float* el4  = (float*)alloc((size_t)16 * N);
  float* er4  = (float*)alloc((size_t)16 * N);
  float* rnrm = (float*)alloc((size_t)4 * N);
  float* cmw1 = (float*)alloc(4 * 272);
  float* cmw2 = (float*)alloc(4 * 80);
  float* out2 = (float*)alloc((size_t)4 * N * 32);   // layer-2 output [N][32]

  hipMemsetAsync(zbase, 0, zbytes, stream);
  hipMemsetAsync(csr_src, 0, (size_t)4 * Emax, stream);

  // CSR build: degree hist + padded rsp scan
  int eb = (E + 255) / 256;
  int nb1024 = (N + 1023) / 1024;
  hist_k<<<eb, 256, 0, stream>>>(dst, counts, E);
  scan1<<<nb1024, 256, 0, stream>>>(counts, rsp, bsum, N);
  scan2<<<1, 128, 0, stream>>>(bsum, nb1024);
  scan3<<<(N + 255) / 256, 256, 0, stream>>>(rsp, bsum, N);

  // 3-pass bucketed counting-sort scatter (single-owner csr lines)
  int nb1024s = (segN + 1023) / 1024;
  bhist_k<<<P2B, 256, 0, stream>>>(dst, bhist, E, NB, chunk);
  pscan1<<<nb1024s, 256, 0, stream>>>(bhist, bhist, bsum2, segN);
  scan2<<<1, 128, 0, stream>>>(bsum2, nb1024s);
  scan3<<<(segN + 255) / 256, 256, 0, stream>>>(bhist, bsum2, segN);
  bscatter_k<<<P2B, 256, 0, stream>>>(src, dst, bhist, ebuf, E, NB, chunk);
  fscatter_k<<<NB, 256, 0, stream>>>(ebuf, bhist, rsp, csr_src, E, NB, P2B, N);

  // weights: [W | W@al | W@ar | pad | resW] transposed, bf16 hi+lo — one launch
  const int packTot = 144 * 64 + 272 * 128 + 80 * 128;
  fill_all<<<(packTot + 255) / 256, 256, 0, stream>>>(W0, al0, ar0, W1, al1, ar1, resW1,
                                                      W2, al2, ar2, resW2, w0t, w1t, w2t);

  const int rowTiles = N / 16;                  // 6250, divisible by R=5
  const int gblocks = (rowTiles / 5 + 3) / 4;   // 1250 waves, 4/block
  const int aggblocks = (N + 3) / 4;            // wave per node

  // Layer 0 (A = x fp32, no colmean fold)
  gemm_bf16<64, 144, 5, 128, 4, 144, true, false><<<gblocks, 256, 0, stream>>>(
      x, w0t, nullptr, feat8, el4, er4, nullptr, rowTiles);
  aggregate4<0><<<aggblocks, 256, 0, stream>>>(feat8, el4, er4, csr_src, rsp, counts, nullptr, vbf, rnrm, N);
  colsum_k<<<512, 256, 0, stream>>>(vbf, rnrm, colsumA, N);
  cmw_k<<<2, 256, 0, stream>>>(colsumA, w1t, cmw1, 128, 272, invN);

  // Layer 1 (A = vbf, colmean folded via cmw1)
  gemm_bf16<128, 272, 5, 128, 4, 144, false, true><<<gblocks, 256, 0, stream>>>(
      vbf, w1t, cmw1, feat8, el4, er4, resh, rowTiles);
  aggregate4<1><<<aggblocks, 256, 0, stream>>>(feat8, el4, er4, csr_src, rsp, counts, resh, vbf, rnrm, N);
  colsum_k<<<512, 256, 0, stream>>>(vbf, rnrm, colsumB, N);
  cmw_k<<<1, 256, 0, stream>>>(colsumB, w2t, cmw2, 128, 80, invN);

  // Layer 2 (A = vbf, colmean folded via cmw2)
  gemm_bf16<128, 80, 5, 32, 1, 48, false, true><<<gblocks, 256, 0, stream>>>(
      vbf, w2t, cmw2, feat8, el4, er4, resh, rowTiles);
  aggregate1<<<aggblocks, 256, 0, stream>>>(feat8, el4, er4, csr_src, rsp, counts, resh, out2, N);
  final_reduce<<<512, 256, 0, stream>>>(out2, outsum, N);
  finalize_k<<<1, 64, 0, stream>>>(outsum, (float*)d_out, invN);
}